// Round 1
// baseline (1061.739 us; speedup 1.0000x reference)
//
#include <hip/hip_runtime.h>
#include <cstdint>

// ---------------- problem constants ----------------
#define BB    2
#define NPTS  65536
#define NCAMS 5
#define NLVLS 3
#define CINC  256
#define MIDC  128
#define OUTCH 128
#define PTSCH 128
#define HH    64
#define WW    112
#define NIMG  10          // BB*NCAMS
#define NROWS 131072      // BB*NPTS

using f32x4  = __attribute__((ext_vector_type(4))) float;
using bf16x8 = __attribute__((ext_vector_type(8))) __bf16;

static __device__ __forceinline__ unsigned short f2bf(float f) {
  unsigned int u = __float_as_uint(f);
  u += 0x7fffu + ((u >> 16) & 1u);     // round-to-nearest-even
  return (unsigned short)(u >> 16);
}
static __device__ __forceinline__ float bflo(uint32_t d) { return __uint_as_float(d << 16); }
static __device__ __forceinline__ float bfhi(uint32_t d) { return __uint_as_float(d & 0xffff0000u); }

// ---------------- ws layout (bytes) ----------------
// imgP   : [10][66][114][256] bf16 (zero-padded NHWC, reused per level)   38,522,880
// fdat   : [3][10][64][112][128] bf16 (folded conv output)                55,050,240
// wf     : [3][ck64:4][tap:9][o:128][c:64] bf16 (folded weights)           1,769,472
// bias   : [3][128] f32 (folded conv bias)                                     1,536
// pts_wb : [128][128] bf16                                                    32,768
// img_raw: [131072][128] bf16                                             33,554,432
// pts_raw: [131072][128] bf16                                             33,554,432
// stats  : [512] f32  (img sum, img sumsq, pts sum, pts sumsq)                 2,048
#define OFF_IMGP   ((size_t)0)
#define SZ_IMGP    ((size_t)38522880)
#define OFF_FDAT   (OFF_IMGP + SZ_IMGP)
#define SZ_FDAT    ((size_t)55050240)
#define OFF_WF     (OFF_FDAT + SZ_FDAT)
#define SZ_WF      ((size_t)1769472)
#define OFF_BIAS   (OFF_WF + SZ_WF)
#define SZ_BIAS    ((size_t)1536)
#define OFF_PTSWB  (OFF_BIAS + SZ_BIAS)
#define SZ_PTSWB   ((size_t)32768)
#define OFF_IRAW   (OFF_PTSWB + SZ_PTSWB)
#define SZ_IRAW    ((size_t)33554432)
#define OFF_PRAW   (OFF_IRAW + SZ_IRAW)
#define SZ_PRAW    ((size_t)33554432)
#define OFF_STATS  (OFF_PRAW + SZ_PRAW)
#define SZ_STATS   ((size_t)2048)

// =====================================================================
// Fold img_w into conv_w:  wf[l][ck64][tap][o][c64] (bf16)
// grid: 3*9*8 = 216 blocks (l, tap, ck32), 256 threads
// =====================================================================
__global__ __launch_bounds__(256) void k_fold_w(const float* __restrict__ img_w,
                                                const float* __restrict__ conv_w,
                                                unsigned short* __restrict__ wf) {
  __shared__ float iw[128 * 130];   // [o][mid], pitch 130
  __shared__ float cw[128 * 33];    // [mid][c32], pitch 33
  const int bid = blockIdx.x;
  const int l = bid / 72, r = bid % 72, tap = r / 8, ck = r % 8;
  const int t = threadIdx.x;
  // stage img_w slice [o 128][mid 128]
  for (int v = t; v < 4096; v += 256) {
    int o = v >> 5, seg = v & 31;
    float4 f = *(const float4*)(img_w + o * 384 + l * 128 + seg * 4);
    float* d = iw + o * 130 + seg * 4;
    d[0] = f.x; d[1] = f.y; d[2] = f.z; d[3] = f.w;
  }
  // stage conv_w chunk [mid 128][c 32]
  for (int v = t; v < 4096; v += 256) {
    int mid = v >> 5, cj = v & 31;
    cw[mid * 33 + cj] = conv_w[(size_t)(((l * 128 + mid) * 256) + (ck * 32 + cj)) * 9 + tap];
  }
  __syncthreads();
  const int o = t & 127, cs = t >> 7;  // each thread: 16 c values
  float accs[16];
  #pragma unroll
  for (int ci = 0; ci < 16; ++ci) accs[ci] = 0.f;
  for (int mid = 0; mid < 128; ++mid) {
    float a = iw[o * 130 + mid];
    #pragma unroll
    for (int ci = 0; ci < 16; ++ci) accs[ci] = fmaf(a, cw[mid * 33 + cs * 16 + ci], accs[ci]);
  }
  unsigned short* dst = wf + (size_t)((((l * 4 + (ck >> 1)) * 9 + tap) * 128 + o) * 64)
                           + (ck & 1) * 32 + cs * 16;
  #pragma unroll
  for (int ci = 0; ci < 16; ++ci) dst[ci] = f2bf(accs[ci]);
}

// =====================================================================
// misc: block 0 -> folded conv bias; blocks 1..64 -> pts_w -> bf16
// =====================================================================
__global__ __launch_bounds__(256) void k_misc(const float* __restrict__ img_w,
                                              const float* __restrict__ conv_b,
                                              const float* __restrict__ pts_w,
                                              float* __restrict__ bias,
                                              unsigned short* __restrict__ pts_wb) {
  const int t = threadIdx.x;
  if (blockIdx.x == 0) {
    if (t < 128) {
      for (int l = 0; l < 3; ++l) {
        float a = 0.f;
        for (int mid = 0; mid < 128; ++mid)
          a = fmaf(img_w[t * 384 + l * 128 + mid], conv_b[l * 128 + mid], a);
        bias[l * 128 + t] = a;
      }
    }
  } else {
    int idx = (blockIdx.x - 1) * 256 + t;   // < 16384
    pts_wb[idx] = f2bf(pts_w[idx]);
  }
}

// =====================================================================
// NCHW fp32 -> padded NHWC bf16 for one level
// grid: 640 (n,y), 256 threads
// =====================================================================
__global__ __launch_bounds__(256) void k_nhwc(const float* __restrict__ img,
                                              unsigned short* __restrict__ imgP, int l) {
  __shared__ unsigned short tile[112 * 258];  // [x][c], pitch 258 (odd word stride)
  const int t = threadIdx.x;
  const int n = blockIdx.x >> 6, y = blockIdx.x & 63;
  const float* src = img + (size_t)(l * 10 + n) * 256 * 7168 + (size_t)y * 112;
  for (int e = t; e < 28672; e += 256) {
    int c = e / 112;
    int x = e - c * 112;
    tile[x * 258 + c] = f2bf(src[(size_t)c * 7168 + x]);
  }
  __syncthreads();
  const uint32_t* t32 = (const uint32_t*)tile;
  uint32_t* dst = (uint32_t*)(imgP + ((size_t)(n * 66 + y + 1) * 114 + 1) * 256);
  for (int v = t; v < 14336; v += 256) {
    int x = v >> 7, cp = v & 127;
    dst[v] = t32[x * 129 + cp];
  }
}

// =====================================================================
// Implicit-GEMM 3x3 conv with folded weights, one (level, image, row) per block.
// M=112 (x), N=128 (oc), K=2304 = (4 ck64) x (3 ky) x (3 kx) x 32
// 16x16x32 bf16 MFMA; 4 waves = (m-half, n-half) 4x4 tile split.
// =====================================================================
#define AP 72   // LDS pitch (elements): 144B rows, 16B-aligned, 4-way-conflict max
__global__ __launch_bounds__(256, 2) void k_conv(const unsigned short* __restrict__ imgP,
                                                 const unsigned short* __restrict__ wf,
                                                 const float* __restrict__ bias,
                                                 unsigned short* __restrict__ fout, int l) {
  __shared__ unsigned short lds[114 * AP + 384 * AP];   // A tile + 3-tap B tile (71.7 KB)
  unsigned short* As = lds;
  unsigned short* Bs = lds + 114 * AP;
  const int t = threadIdx.x, lane = t & 63, wave = t >> 6;
  const int n = blockIdx.x >> 6, y = blockIdx.x & 63;
  const int mh = wave & 1, nh = wave >> 1;
  const int mb = mh * 64, nb = nh * 64;
  const int m = lane & 15, kq = lane >> 4;
  const int NMT = mh ? 3 : 4;   // m-half 1 covers x 64..111 (3 tiles)

  f32x4 acc[4][4];
  #pragma unroll
  for (int i = 0; i < 4; ++i)
    #pragma unroll
    for (int j = 0; j < 4; ++j) acc[i][j] = (f32x4){0.f, 0.f, 0.f, 0.f};

  const unsigned short* imgbase = imgP + (size_t)n * 66 * 114 * 256;

  for (int ck = 0; ck < 4; ++ck) {
    for (int ky = 0; ky < 3; ++ky) {
      __syncthreads();
      {  // stage A: [xp 0..113][c 64] from padded row y+ky
        const unsigned short* srcA = imgbase + (size_t)(y + ky) * 114 * 256 + ck * 64;
        for (int v = t; v < 912; v += 256) {
          int xp = v >> 3, seg = v & 7;
          uint4 d = *(const uint4*)(srcA + xp * 256 + seg * 8);
          *(uint4*)(As + xp * AP + seg * 8) = d;
        }
        // stage B: 3 kx taps x [o 128][c 64]
        const unsigned short* srcB = wf + (size_t)(((l * 4 + ck) * 9 + ky * 3) * 128) * 64;
        for (int v = t; v < 3072; v += 256) {
          int row = v >> 3, seg = v & 7;
          uint4 d = *(const uint4*)(srcB + (size_t)row * 64 + seg * 8);
          *(uint4*)(Bs + row * AP + seg * 8) = d;
        }
      }
      __syncthreads();
      #pragma unroll
      for (int kx = 0; kx < 3; ++kx) {
        bf16x8 bfr[4][2];
        #pragma unroll
        for (int nt = 0; nt < 4; ++nt) {
          const unsigned short* bp = Bs + (kx * 128 + nb + nt * 16 + m) * AP + kq * 8;
          bfr[nt][0] = *(const bf16x8*)(bp);
          bfr[nt][1] = *(const bf16x8*)(bp + 32);
        }
        #pragma unroll
        for (int mt = 0; mt < 4; ++mt) {
          if (mt < NMT) {
            const unsigned short* ap = As + (kx + mb + mt * 16 + m) * AP + kq * 8;
            bf16x8 a0 = *(const bf16x8*)(ap);
            bf16x8 a1 = *(const bf16x8*)(ap + 32);
            #pragma unroll
            for (int nt = 0; nt < 4; ++nt) {
              acc[mt][nt] = __builtin_amdgcn_mfma_f32_16x16x32_bf16(a0, bfr[nt][0], acc[mt][nt], 0, 0, 0);
              acc[mt][nt] = __builtin_amdgcn_mfma_f32_16x16x32_bf16(a1, bfr[nt][1], acc[mt][nt], 0, 0, 0);
            }
          }
        }
      }
    }
  }

  // epilogue: bias + bf16, repack via LDS for coalesced global stores
  __syncthreads();
  unsigned short* Ep = lds;   // [112][128]
  #pragma unroll
  for (int mt = 0; mt < 4; ++mt) {
    if (mt < NMT) {
      #pragma unroll
      for (int nt = 0; nt < 4; ++nt) {
        int oc = nb + nt * 16 + m;
        float bv = bias[l * 128 + oc];
        #pragma unroll
        for (int rr = 0; rr < 4; ++rr) {
          int x = mb + mt * 16 + kq * 4 + rr;
          Ep[x * 128 + oc] = f2bf(acc[mt][nt][rr] + bv);
        }
      }
    }
  }
  __syncthreads();
  unsigned short* dst = fout + (size_t)((l * 10 + n) * 64 + y) * (112 * 128);
  for (int v = t; v < 1792; v += 256)
    *(uint4*)(dst + v * 8) = *(const uint4*)(Ep + v * 8);
}

// =====================================================================
// projection + 3-level bilinear gather -> img_raw (bf16)
// one wave per point (x4 points per wave), lane covers 2 channels
// =====================================================================
#define LSTRIDE32 ((size_t)4587520)   // level stride in u32 (10*64*112*64)
__global__ __launch_bounds__(256) void k_gather(const float* __restrict__ pts_xyz,
                                                const int* __restrict__ cam_ids,
                                                const float* __restrict__ Tm,
                                                const float* __restrict__ Km,
                                                const unsigned short* __restrict__ fdat,
                                                unsigned short* __restrict__ img_raw) {
  const int t = threadIdx.x, lane = t & 63, wave = t >> 6;
  const int p0 = blockIdx.x * 16 + wave * 4;
  const uint32_t* fq = (const uint32_t*)fdat;
  for (int j = 0; j < 4; ++j) {
    const int p = p0 + j;
    const int b = p >> 16;
    const int cam = cam_ids[p];
    const float X = pts_xyz[(size_t)p * 3], Y = pts_xyz[(size_t)p * 3 + 1], Z = pts_xyz[(size_t)p * 3 + 2];
    const float* Tc = Tm + cam * 16;
    float pcx = Tc[0] * X + Tc[1] * Y + Tc[2]  * Z + Tc[3];
    float pcy = Tc[4] * X + Tc[5] * Y + Tc[6]  * Z + Tc[7];
    float pcz = Tc[8] * X + Tc[9] * Y + Tc[10] * Z + Tc[11];
    const float* Kc = Km + cam * 9;
    float pimx = Kc[0] * 0.125f * pcx + Kc[1] * pcy          + Kc[2] * 0.125f * pcz;
    float pimy = Kc[3] * pcx          + Kc[4] * 0.125f * pcy + Kc[5] * 0.125f * pcz;
    float pimz = Kc[6] * pcx          + Kc[7] * pcy          + Kc[8] * pcz;
    float u = pimx / pimz, vv = pimy / pimz;
    float gx = u / 112.f * 2.f - 1.f;
    float gy = vv / 64.f * 2.f - 1.f;
    float px = (gx + 1.f) * 0.5f * 111.f;
    float py = (gy + 1.f) * 0.5f * 63.f;
    float x0 = floorf(px), y0 = floorf(py);
    float wx = px - x0, wy = py - y0;
    float cxf[4] = {x0, x0 + 1.f, x0, x0 + 1.f};
    float cyf[4] = {y0, y0, y0 + 1.f, y0 + 1.f};
    float cwt[4] = {(1.f - wx) * (1.f - wy), wx * (1.f - wy), (1.f - wx) * wy, wx * wy};
    const int nimg = b * 5 + cam;
    float wv[4]; int idx[4]; bool any = false;
    #pragma unroll
    for (int c4 = 0; c4 < 4; ++c4) {
      float xf = cxf[c4], yf = cyf[c4];
      bool valid = (xf >= 0.f) && (xf <= 111.f) && (yf >= 0.f) && (yf <= 63.f);
      float w = cwt[c4] * (valid ? 1.f : 0.f);
      int xi = (int)fminf(fmaxf(xf, 0.f), 111.f);
      int yi = (int)fminf(fmaxf(yf, 0.f), 63.f);
      wv[c4] = w;
      idx[c4] = (nimg * 64 + yi) * 112 + xi;
      any = any || (w != 0.f);
    }
    float acc0 = 0.f, acc1 = 0.f;
    if (any) {
      #pragma unroll
      for (int c4 = 0; c4 < 4; ++c4) {
        const uint32_t* q = fq + (size_t)idx[c4] * 64 + lane;
        float w = wv[c4];
        #pragma unroll
        for (int lv = 0; lv < 3; ++lv) {
          uint32_t d = q[lv * LSTRIDE32];
          acc0 = fmaf(w, bflo(d), acc0);
          acc1 = fmaf(w, bfhi(d), acc1);
        }
      }
    }
    ((uint32_t*)img_raw)[(size_t)p * 64 + lane] =
        (uint32_t)f2bf(acc0) | ((uint32_t)f2bf(acc1) << 16);
  }
}

// =====================================================================
// pts GEMM: [131072,128] fp32 @ pts_w.T -> pts_raw bf16, 128-row tiles
// =====================================================================
#define PP 136
__global__ __launch_bounds__(256, 2) void k_ptsgemm(const float* __restrict__ pts_feats,
                                                    const unsigned short* __restrict__ pts_wb,
                                                    unsigned short* __restrict__ pts_raw) {
  __shared__ unsigned short Asm[128 * PP];
  __shared__ unsigned short Bsm[128 * PP];
  const int t = threadIdx.x, lane = t & 63, wave = t >> 6;
  const int mh = wave & 1, nh = wave >> 1;
  const int m = lane & 15, kq = lane >> 4;
  const size_t r0 = (size_t)blockIdx.x * 128;
  for (int v = t; v < 2048; v += 256) {
    int o = v >> 4, seg = v & 15;
    *(uint4*)(Bsm + o * PP + seg * 8) = *(const uint4*)(pts_wb + o * 128 + seg * 8);
  }
  for (int v = t; v < 4096; v += 256) {
    int mm = v >> 5, seg = v & 31;
    float4 f = *(const float4*)(pts_feats + (r0 + mm) * 128 + seg * 4);
    uint2 d;
    d.x = (uint32_t)f2bf(f.x) | ((uint32_t)f2bf(f.y) << 16);
    d.y = (uint32_t)f2bf(f.z) | ((uint32_t)f2bf(f.w) << 16);
    *(uint2*)(Asm + mm * PP + seg * 4) = d;
  }
  __syncthreads();
  f32x4 acc[4][4];
  #pragma unroll
  for (int i = 0; i < 4; ++i)
    #pragma unroll
    for (int jj = 0; jj < 4; ++jj) acc[i][jj] = (f32x4){0.f, 0.f, 0.f, 0.f};
  #pragma unroll
  for (int ks = 0; ks < 4; ++ks) {
    bf16x8 bfr[4];
    #pragma unroll
    for (int nt = 0; nt < 4; ++nt)
      bfr[nt] = *(const bf16x8*)(Bsm + (nh * 64 + nt * 16 + m) * PP + ks * 32 + kq * 8);
    #pragma unroll
    for (int mt = 0; mt < 4; ++mt) {
      bf16x8 af = *(const bf16x8*)(Asm + (mh * 64 + mt * 16 + m) * PP + ks * 32 + kq * 8);
      #pragma unroll
      for (int nt = 0; nt < 4; ++nt)
        acc[mt][nt] = __builtin_amdgcn_mfma_f32_16x16x32_bf16(af, bfr[nt], acc[mt][nt], 0, 0, 0);
    }
  }
  __syncthreads();
  #pragma unroll
  for (int mt = 0; mt < 4; ++mt)
    #pragma unroll
    for (int nt = 0; nt < 4; ++nt)
      #pragma unroll
      for (int rr = 0; rr < 4; ++rr)
        Asm[(mh * 64 + mt * 16 + kq * 4 + rr) * 128 + nh * 64 + nt * 16 + m] = f2bf(acc[mt][nt][rr]);
  __syncthreads();
  unsigned short* dst = pts_raw + r0 * 128;
  for (int v = t; v < 2048; v += 256)
    *(uint4*)(dst + v * 8) = *(const uint4*)(Asm + v * 8);
}

// =====================================================================
// column sum / sumsq for both raw buffers (BN batch statistics)
// grid 512: blocks 0..255 img, 256..511 pts; 512 rows per block
// =====================================================================
__global__ __launch_bounds__(256) void k_stats(const unsigned short* __restrict__ img_raw,
                                               const unsigned short* __restrict__ pts_raw,
                                               float* __restrict__ stats) {
  const int bid = blockIdx.x;
  const uint32_t* src = (const uint32_t*)((bid < 256) ? img_raw : pts_raw);
  const int blk = bid & 255;
  const int t = threadIdx.x, cp = t & 63, rg = t >> 6;
  float s0 = 0.f, q0 = 0.f, s1 = 0.f, q1 = 0.f;
  for (int i = 0; i < 128; ++i) {
    int row = blk * 512 + rg * 128 + i;
    uint32_t d = src[(size_t)row * 64 + cp];
    float v0 = bflo(d), v1 = bfhi(d);
    s0 += v0; q0 += v0 * v0; s1 += v1; q1 += v1 * v1;
  }
  const int base = (bid < 256) ? 0 : 256;
  atomicAdd(&stats[base + 2 * cp], s0);
  atomicAdd(&stats[base + 2 * cp + 1], s1);
  atomicAdd(&stats[base + 128 + 2 * cp], q0);
  atomicAdd(&stats[base + 128 + 2 * cp + 1], q1);
}

// =====================================================================
// finalize: out = relu(a_img*img + a_pts*pts + c) per column, fp32 out
// =====================================================================
__global__ __launch_bounds__(256) void k_final(const unsigned short* __restrict__ img_raw,
                                               const unsigned short* __restrict__ pts_raw,
                                               const float* __restrict__ stats,
                                               const float* __restrict__ img_gamma,
                                               const float* __restrict__ img_beta,
                                               const float* __restrict__ pts_gamma,
                                               const float* __restrict__ pts_beta,
                                               float* __restrict__ out) {
  __shared__ float sA[128], sB[128], sC[128];
  const int t = threadIdx.x;
  if (t < 128) {
    const float Nr = 131072.f;
    float mu_i = stats[t] / Nr;
    float var_i = stats[128 + t] / Nr - mu_i * mu_i;
    float a_i = img_gamma[t] * rsqrtf(var_i + 1e-3f);
    float mu_p = stats[256 + t] / Nr;
    float var_p = stats[384 + t] / Nr - mu_p * mu_p;
    float a_p = pts_gamma[t] * rsqrtf(var_p + 1e-3f);
    sA[t] = a_i; sB[t] = a_p;
    sC[t] = img_beta[t] + pts_beta[t] - a_i * mu_i - a_p * mu_p;
  }
  __syncthreads();
  const uint32_t* ir = (const uint32_t*)img_raw;
  const uint32_t* pr = (const uint32_t*)pts_raw;
  size_t g0 = (size_t)blockIdx.x * 2048;
  for (int i = 0; i < 8; ++i) {
    size_t g = g0 + i * 256 + t;
    uint32_t di = ir[g], dp = pr[g];
    int c = (int)(g & 63) * 2;
    float o0 = fmaxf(0.f, sA[c] * bflo(di) + sB[c] * bflo(dp) + sC[c]);
    float o1 = fmaxf(0.f, sA[c + 1] * bfhi(di) + sB[c + 1] * bfhi(dp) + sC[c + 1]);
    float2 o; o.x = o0; o.y = o1;
    *(float2*)(out + g * 2) = o;
  }
}

// =====================================================================
extern "C" void kernel_launch(void* const* d_in, const int* in_sizes, int n_in,
                              void* d_out, int out_size, void* d_ws, size_t ws_size,
                              hipStream_t stream) {
  const float* img_feats = (const float*)d_in[0];
  const float* pts_xyz   = (const float*)d_in[1];
  const float* pts_feats = (const float*)d_in[2];
  const float* Tm        = (const float*)d_in[3];
  const float* Km        = (const float*)d_in[4];
  const float* conv_w    = (const float*)d_in[5];
  const float* conv_b    = (const float*)d_in[6];
  const float* img_w     = (const float*)d_in[7];
  // d_in[8] img_b, d_in[12] pts_b: cancel under BN mean subtraction
  const float* img_gamma = (const float*)d_in[9];
  const float* img_beta  = (const float*)d_in[10];
  const float* pts_w     = (const float*)d_in[11];
  const float* pts_gamma = (const float*)d_in[13];
  const float* pts_beta  = (const float*)d_in[14];
  const int*   cam_ids   = (const int*)d_in[15];

  char* wsb = (char*)d_ws;
  unsigned short* imgP    = (unsigned short*)(wsb + OFF_IMGP);
  unsigned short* fdat    = (unsigned short*)(wsb + OFF_FDAT);
  unsigned short* wf      = (unsigned short*)(wsb + OFF_WF);
  float*          bias    = (float*)(wsb + OFF_BIAS);
  unsigned short* pts_wb  = (unsigned short*)(wsb + OFF_PTSWB);
  unsigned short* img_raw = (unsigned short*)(wsb + OFF_IRAW);
  unsigned short* pts_raw = (unsigned short*)(wsb + OFF_PRAW);
  float*          stats   = (float*)(wsb + OFF_STATS);

  hipMemsetAsync(imgP, 0, SZ_IMGP, stream);     // zero borders for SAME padding
  hipMemsetAsync(stats, 0, SZ_STATS, stream);

  k_fold_w<<<dim3(216), dim3(256), 0, stream>>>(img_w, conv_w, wf);
  k_misc<<<dim3(65), dim3(256), 0, stream>>>(img_w, conv_b, pts_w, bias, pts_wb);

  for (int l = 0; l < 3; ++l) {
    k_nhwc<<<dim3(640), dim3(256), 0, stream>>>(img_feats, imgP, l);
    k_conv<<<dim3(640), dim3(256), 0, stream>>>(imgP, wf, bias, fdat, l);
  }

  k_gather<<<dim3(8192), dim3(256), 0, stream>>>(pts_xyz, cam_ids, Tm, Km, fdat, img_raw);
  k_ptsgemm<<<dim3(1024), dim3(256), 0, stream>>>(pts_feats, pts_wb, pts_raw);
  k_stats<<<dim3(512), dim3(256), 0, stream>>>(img_raw, pts_raw, stats);
  k_final<<<dim3(4096), dim3(256), 0, stream>>>(img_raw, pts_raw, stats,
                                                img_gamma, img_beta, pts_gamma, pts_beta,
                                                (float*)d_out);
}

// Round 2
// 753.907 us; speedup vs baseline: 1.4083x; 1.4083x over previous
//
#include <hip/hip_runtime.h>
#include <cstdint>

// ---------------- problem constants ----------------
#define LVLPOS 75240          // 10*66*114 flat padded positions per level
#define GUARD  256            // zero guard positions before/after imgP data
#define NPOST  75264          // 588*128 (fdat padded position count)

using f32x4  = __attribute__((ext_vector_type(4))) float;
using bf16x8 = __attribute__((ext_vector_type(8))) __bf16;

static __device__ __forceinline__ unsigned short f2bf(float f) {
  unsigned int u = __float_as_uint(f);
  u += 0x7fffu + ((u >> 16) & 1u);     // round-to-nearest-even
  return (unsigned short)(u >> 16);
}
static __device__ __forceinline__ float bflo(uint32_t d) { return __uint_as_float(d << 16); }
static __device__ __forceinline__ float bfhi(uint32_t d) { return __uint_as_float(d & 0xffff0000u); }

#if __has_builtin(__builtin_amdgcn_global_load_lds)
#define HAVE_GLL 1
typedef const __attribute__((address_space(1))) unsigned int* gas1_t;
typedef __attribute__((address_space(3))) unsigned int* las3_t;
static __device__ __forceinline__ void gll16(const void* g, void* l) {
  __builtin_amdgcn_global_load_lds((gas1_t)g, (las3_t)l, 16, 0, 0);
}
#else
#define HAVE_GLL 0
#endif

// ---------------- ws layout (bytes) ----------------
// wf     : [3][ck64:4][tap:9][frag 8192] bf16 (fragment-major folded W)  1,769,472
// bias   : [128] f32 (folded conv bias, summed over levels)                    512
// pts_wb : [128][128] bf16                                                  32,768
// stats  : [512] f32                                                         2,048
// fdat   : [75264][128] bf16 (level-summed conv output, padded layout)  19,267,584
// imgP   : [(256+3*75240+256)][256] bf16 flat padded NHWC               115,830,784
// img_raw/pts_raw (each 33,554,432) ALIAS imgP (dead after k_conv)
#define OFF_WF     ((size_t)0)
#define OFF_BIAS   ((size_t)1769472)
#define OFF_PTSWB  ((size_t)1769984)
#define OFF_STATS  ((size_t)1802752)
#define OFF_FDAT   ((size_t)1804800)
#define OFF_IMGP   ((size_t)21072384)
#define OFF_IRAW   OFF_IMGP
#define OFF_PRAW   (OFF_IMGP + (size_t)33554432)

// =====================================================================
// zero imgP guard regions + per-image pad rows (3.8 MB total)
// grid 62: b0/b1 = head/tail guard, b2..61 = (lvl, img, top/bottom row)
// =====================================================================
__global__ __launch_bounds__(256) void k_zero(unsigned short* __restrict__ imgP) {
  const int b = blockIdx.x, t = threadIdx.x;
  size_t base; int n16;
  if (b == 0)      { base = 0;                          n16 = 8192; }
  else if (b == 1) { base = (size_t)(GUARD + 3 * LVLPOS) * 256; n16 = 8192; }
  else {
    int z = b - 2, lvl = z / 20, w = z % 20, n = w >> 1, y = (w & 1) ? 65 : 0;
    base = (size_t)(GUARD + lvl * LVLPOS + (n * 66 + y) * 114) * 256;
    n16 = 3648;
  }
  uint4 zz = {0u, 0u, 0u, 0u};
  uint4* d = (uint4*)(imgP + base);
  for (int v = t; v < n16; v += 256) d[v] = zz;
}

// =====================================================================
// Fold img_w into conv_w -> fragment-major wf[l][ck64][tap][8192]
// frag layout: [nt:8][kh:2][lane:64][elem:8]  (lane = (o&15) + 16*kq)
// grid 216 = (l, tap, ck32), 256 threads
// =====================================================================
__global__ __launch_bounds__(256) void k_fold_w(const float* __restrict__ img_w,
                                                const float* __restrict__ conv_w,
                                                unsigned short* __restrict__ wf) {
  __shared__ float iw[128 * 130];
  __shared__ float cw[128 * 33];
  const int bid = blockIdx.x;
  const int l = bid / 72, r = bid % 72, tap = r / 8, ckk = r % 8;
  const int t = threadIdx.x;
  for (int v = t; v < 4096; v += 256) {
    int o = v >> 5, seg = v & 31;
    float4 f = *(const float4*)(img_w + o * 384 + l * 128 + seg * 4);
    float* d = iw + o * 130 + seg * 4;
    d[0] = f.x; d[1] = f.y; d[2] = f.z; d[3] = f.w;
  }
  for (int v = t; v < 4096; v += 256) {
    int mid = v >> 5, cj = v & 31;
    cw[mid * 33 + cj] = conv_w[(size_t)(((l * 128 + mid) * 256) + (ckk * 32 + cj)) * 9 + tap];
  }
  __syncthreads();
  const int o = t & 127, cs = t >> 7;
  float accs[16];
  #pragma unroll
  for (int ci = 0; ci < 16; ++ci) accs[ci] = 0.f;
  for (int mid = 0; mid < 128; ++mid) {
    float a = iw[o * 130 + mid];
    #pragma unroll
    for (int ci = 0; ci < 16; ++ci) accs[ci] = fmaf(a, cw[mid * 33 + cs * 16 + ci], accs[ci]);
  }
  const int nt = o >> 4;
  #pragma unroll
  for (int ci = 0; ci < 16; ++ci) {
    int c = ckk * 32 + cs * 16 + ci;       // global input channel 0..255
    int ck64 = c >> 6, c64 = c & 63;
    int kh = c64 >> 5, kq3 = (c64 >> 3) & 3, el = c64 & 7;
    int lane = (o & 15) + (kq3 << 4);
    size_t idx = (size_t)((l * 4 + ck64) * 9 + tap) * 8192
               + (size_t)((nt * 2 + kh) * 512) + lane * 8 + el;
    wf[idx] = f2bf(accs[ci]);
  }
}

// =====================================================================
// misc: block 0 -> folded conv bias (summed over levels); 1..64 -> pts_w bf16
// =====================================================================
__global__ __launch_bounds__(256) void k_misc(const float* __restrict__ img_w,
                                              const float* __restrict__ conv_b,
                                              const float* __restrict__ pts_w,
                                              float* __restrict__ bias,
                                              unsigned short* __restrict__ pts_wb) {
  const int t = threadIdx.x;
  if (blockIdx.x == 0) {
    if (t < 128) {
      float a = 0.f;
      for (int i = 0; i < 384; ++i) a = fmaf(img_w[t * 384 + i], conv_b[i], a);
      bias[t] = a;
    }
  } else {
    int idx = (blockIdx.x - 1) * 256 + t;
    pts_wb[idx] = f2bf(pts_w[idx]);
  }
}

// =====================================================================
// NCHW fp32 -> flat padded NHWC bf16 (writes full 114-pos rows, x-pads zero)
// grid 1920 = (lvl, n, y)
// =====================================================================
__global__ __launch_bounds__(256) void k_nhwc(const float* __restrict__ img,
                                              unsigned short* __restrict__ imgP) {
  __shared__ unsigned short tile[256 * 114];   // [c][x]
  const int t = threadIdx.x;
  const int lvl = blockIdx.x / 640, r = blockIdx.x % 640, n = r >> 6, y = r & 63;
  const float4* src4 = (const float4*)(img + (size_t)(lvl * 10 + n) * 1835008 + (size_t)y * 112);
  for (int v = t; v < 7168; v += 256) {
    int c = v / 28, s = v - c * 28;
    float4 f = src4[(size_t)c * 1792 + s];
    uint2 d;
    d.x = (uint32_t)f2bf(f.x) | ((uint32_t)f2bf(f.y) << 16);
    d.y = (uint32_t)f2bf(f.z) | ((uint32_t)f2bf(f.w) << 16);
    *(uint2*)(tile + c * 114 + s * 4) = d;
  }
  __syncthreads();
  uint32_t* dst = (uint32_t*)(imgP + (size_t)(GUARD + lvl * LVLPOS + (n * 66 + y + 1) * 114) * 256);
  for (int v = t; v < 14592; v += 256) {
    int xp = v >> 7, cp = v & 127;
    uint32_t val = 0;
    if (xp >= 1 && xp <= 112) {
      int x = xp - 1;
      val = (uint32_t)tile[(2 * cp) * 114 + x] | ((uint32_t)tile[(2 * cp + 1) * 114 + x] << 16);
    }
    dst[v] = val;
  }
}

// =====================================================================
// Level-summed implicit-GEMM conv: M=128 flat pos, N=128 oc, K=6912
// 36 (lvl,ck,ky) stages x 3 kx sub-stages; A halo in LDS (pitch 72),
// B fragment-major double-buffered via global_load_lds. LDS 51488 B.
// =====================================================================
__global__ __launch_bounds__(256, 3) void k_conv(const unsigned short* __restrict__ imgP,
                                                 const unsigned short* __restrict__ wf,
                                                 const float* __restrict__ bias,
                                                 unsigned short* __restrict__ fdat) {
  __shared__ unsigned short lds[9360 + 2 * 8192];
  unsigned short* As = lds;
  unsigned short* Bs = lds + 9360;
  const int t = threadIdx.x, lane = t & 63, wave = t >> 6;
  const int mh = wave & 1, nh = wave >> 1;
  const int m = lane & 15, kq = lane >> 4;
  const int m0 = blockIdx.x * 128;

  f32x4 acc[4][4];
  #pragma unroll
  for (int i = 0; i < 4; ++i)
    #pragma unroll
    for (int j = 0; j < 4; ++j) acc[i][j] = (f32x4){0.f, 0.f, 0.f, 0.f};

  for (int lvl = 0; lvl < 3; ++lvl) {
    const unsigned short* Alvl = imgP + ((size_t)GUARD + (size_t)lvl * LVLPOS + m0 - 1) * 256;
    for (int ck = 0; ck < 4; ++ck) {
      for (int ky = 0; ky < 3; ++ky) {
        // ---- stage A halo (130 pos x 64 c) into LDS, pitch 72 ----
        const unsigned short* Asrc = Alvl + (ptrdiff_t)(ky - 1) * 114 * 256 + ck * 64;
        for (int v = t; v < 1040; v += 256) {
          int p = v >> 3, seg = v & 7;
          uint4 d = *(const uint4*)(Asrc + (size_t)p * 256 + seg * 8);
          *(uint4*)(As + p * 72 + seg * 8) = d;
        }
        // ---- stage B tap kx=0 into buf0 ----
        const unsigned short* Bsrc = wf + (size_t)((lvl * 4 + ck) * 9 + ky * 3) * 8192;
#if HAVE_GLL
        #pragma unroll
        for (int i = 0; i < 4; ++i) {
          int chunk = wave * 4 + i;
          gll16(Bsrc + chunk * 512 + lane * 8, Bs + chunk * 512);
        }
#else
        for (int v = t; v < 1024; v += 256)
          *(uint4*)(Bs + v * 8) = *(const uint4*)(Bsrc + v * 8);
#endif
        __syncthreads();
        #pragma unroll
        for (int kx = 0; kx < 3; ++kx) {
          if (kx < 2) {  // prefetch next tap into other buffer
            const unsigned short* Bn = Bsrc + (kx + 1) * 8192;
            unsigned short* Bd = Bs + ((kx + 1) & 1) * 8192;
#if HAVE_GLL
            #pragma unroll
            for (int i = 0; i < 4; ++i) {
              int chunk = wave * 4 + i;
              gll16(Bn + chunk * 512 + lane * 8, Bd + chunk * 512);
            }
#else
            for (int v = t; v < 1024; v += 256)
              *(uint4*)(Bd + v * 8) = *(const uint4*)(Bn + v * 8);
#endif
          }
          const unsigned short* Bb = Bs + (kx & 1) * 8192;
          bf16x8 bfr[4][2];
          #pragma unroll
          for (int nt = 0; nt < 4; ++nt) {
            const unsigned short* bp = Bb + ((nh * 4 + nt) * 2) * 512 + lane * 8;
            bfr[nt][0] = *(const bf16x8*)(bp);
            bfr[nt][1] = *(const bf16x8*)(bp + 512);
          }
          #pragma unroll
          for (int mt = 0; mt < 4; ++mt) {
            const unsigned short* ap = As + (mh * 64 + mt * 16 + m + kx) * 72 + kq * 8;
            bf16x8 a0 = *(const bf16x8*)(ap);
            bf16x8 a1 = *(const bf16x8*)(ap + 32);
            #pragma unroll
            for (int nt = 0; nt < 4; ++nt) {
              acc[mt][nt] = __builtin_amdgcn_mfma_f32_16x16x32_bf16(a0, bfr[nt][0], acc[mt][nt], 0, 0, 0);
              acc[mt][nt] = __builtin_amdgcn_mfma_f32_16x16x32_bf16(a1, bfr[nt][1], acc[mt][nt], 0, 0, 0);
            }
          }
          __syncthreads();
        }
      }
    }
  }

  // ---- epilogue: bias + bf16, LDS repack, contiguous store ----
  unsigned short* Ep = lds;
  #pragma unroll
  for (int nt = 0; nt < 4; ++nt) {
    int oc = nh * 64 + nt * 16 + m;
    float bv = bias[oc];
    #pragma unroll
    for (int mt = 0; mt < 4; ++mt)
      #pragma unroll
      for (int rr = 0; rr < 4; ++rr)
        Ep[(mh * 64 + mt * 16 + kq * 4 + rr) * 128 + oc] = f2bf(acc[mt][nt][rr] + bv);
  }
  __syncthreads();
  unsigned short* dst = fdat + (size_t)m0 * 128;
  for (int v = t; v < 2048; v += 256)
    *(uint4*)(dst + v * 8) = *(const uint4*)(Ep + v * 8);
}

// =====================================================================
// projection + bilinear gather from level-summed fdat -> img_raw bf16
// =====================================================================
__global__ __launch_bounds__(256) void k_gather(const float* __restrict__ pts_xyz,
                                                const int* __restrict__ cam_ids,
                                                const float* __restrict__ Tm,
                                                const float* __restrict__ Km,
                                                const unsigned short* __restrict__ fdat,
                                                unsigned short* __restrict__ img_raw) {
  const int t = threadIdx.x, lane = t & 63, wave = t >> 6;
  const int p0 = blockIdx.x * 16 + wave * 4;
  const uint32_t* fq = (const uint32_t*)fdat;
  for (int j = 0; j < 4; ++j) {
    const int p = p0 + j;
    const int b = p >> 16;
    const int cam = cam_ids[p];
    const float X = pts_xyz[(size_t)p * 3], Y = pts_xyz[(size_t)p * 3 + 1], Z = pts_xyz[(size_t)p * 3 + 2];
    const float* Tc = Tm + cam * 16;
    float pcx = Tc[0] * X + Tc[1] * Y + Tc[2]  * Z + Tc[3];
    float pcy = Tc[4] * X + Tc[5] * Y + Tc[6]  * Z + Tc[7];
    float pcz = Tc[8] * X + Tc[9] * Y + Tc[10] * Z + Tc[11];
    const float* Kc = Km + cam * 9;
    float pimx = Kc[0] * 0.125f * pcx + Kc[1] * pcy          + Kc[2] * 0.125f * pcz;
    float pimy = Kc[3] * pcx          + Kc[4] * 0.125f * pcy + Kc[5] * 0.125f * pcz;
    float pimz = Kc[6] * pcx          + Kc[7] * pcy          + Kc[8] * pcz;
    float u = pimx / pimz, vv = pimy / pimz;
    float px = (u / 112.f) * 111.f;
    float py = (vv / 64.f) * 63.f;
    float x0 = floorf(px), y0 = floorf(py);
    float wx = px - x0, wy = py - y0;
    float cxf[4] = {x0, x0 + 1.f, x0, x0 + 1.f};
    float cyf[4] = {y0, y0, y0 + 1.f, y0 + 1.f};
    float cwt[4] = {(1.f - wx) * (1.f - wy), wx * (1.f - wy), (1.f - wx) * wy, wx * wy};
    const int nimg = b * 5 + cam;
    float wv[4]; int idx[4]; bool any = false;
    #pragma unroll
    for (int c4 = 0; c4 < 4; ++c4) {
      float xf = cxf[c4], yf = cyf[c4];
      bool valid = (xf >= 0.f) && (xf <= 111.f) && (yf >= 0.f) && (yf <= 63.f);
      float w = cwt[c4] * (valid ? 1.f : 0.f);
      int xi = (int)fminf(fmaxf(xf, 0.f), 111.f);
      int yi = (int)fminf(fmaxf(yf, 0.f), 63.f);
      wv[c4] = w;
      idx[c4] = (nimg * 66 + yi + 1) * 114 + xi + 1;   // padded flat pos
      any = any || (w != 0.f);
    }
    float acc0 = 0.f, acc1 = 0.f;
    if (any) {
      #pragma unroll
      for (int c4 = 0; c4 < 4; ++c4) {
        uint32_t d = fq[(size_t)idx[c4] * 64 + lane];
        acc0 = fmaf(wv[c4], bflo(d), acc0);
        acc1 = fmaf(wv[c4], bfhi(d), acc1);
      }
    }
    ((uint32_t*)img_raw)[(size_t)p * 64 + lane] =
        (uint32_t)f2bf(acc0) | ((uint32_t)f2bf(acc1) << 16);
  }
}

// =====================================================================
// pts GEMM: [131072,128] fp32 @ pts_w.T -> pts_raw bf16
// =====================================================================
#define PP 136
__global__ __launch_bounds__(256, 2) void k_ptsgemm(const float* __restrict__ pts_feats,
                                                    const unsigned short* __restrict__ pts_wb,
                                                    unsigned short* __restrict__ pts_raw) {
  __shared__ unsigned short Asm[128 * PP];
  __shared__ unsigned short Bsm[128 * PP];
  const int t = threadIdx.x, lane = t & 63, wave = t >> 6;
  const int mh = wave & 1, nh = wave >> 1;
  const int m = lane & 15, kq = lane >> 4;
  const size_t r0 = (size_t)blockIdx.x * 128;
  for (int v = t; v < 2048; v += 256) {
    int o = v >> 4, seg = v & 15;
    *(uint4*)(Bsm + o * PP + seg * 8) = *(const uint4*)(pts_wb + o * 128 + seg * 8);
  }
  for (int v = t; v < 4096; v += 256) {
    int mm = v >> 5, seg = v & 31;
    float4 f = *(const float4*)(pts_feats + (r0 + mm) * 128 + seg * 4);
    uint2 d;
    d.x = (uint32_t)f2bf(f.x) | ((uint32_t)f2bf(f.y) << 16);
    d.y = (uint32_t)f2bf(f.z) | ((uint32_t)f2bf(f.w) << 16);
    *(uint2*)(Asm + mm * PP + seg * 4) = d;
  }
  __syncthreads();
  f32x4 acc[4][4];
  #pragma unroll
  for (int i = 0; i < 4; ++i)
    #pragma unroll
    for (int jj = 0; jj < 4; ++jj) acc[i][jj] = (f32x4){0.f, 0.f, 0.f, 0.f};
  #pragma unroll
  for (int ks = 0; ks < 4; ++ks) {
    bf16x8 bfr[4];
    #pragma unroll
    for (int nt = 0; nt < 4; ++nt)
      bfr[nt] = *(const bf16x8*)(Bsm + (nh * 64 + nt * 16 + m) * PP + ks * 32 + kq * 8);
    #pragma unroll
    for (int mt = 0; mt < 4; ++mt) {
      bf16x8 af = *(const bf16x8*)(Asm + (mh * 64 + mt * 16 + m) * PP + ks * 32 + kq * 8);
      #pragma unroll
      for (int nt = 0; nt < 4; ++nt)
        acc[mt][nt] = __builtin_amdgcn_mfma_f32_16x16x32_bf16(af, bfr[nt], acc[mt][nt], 0, 0, 0);
    }
  }
  __syncthreads();
  #pragma unroll
  for (int mt = 0; mt < 4; ++mt)
    #pragma unroll
    for (int nt = 0; nt < 4; ++nt)
      #pragma unroll
      for (int rr = 0; rr < 4; ++rr)
        Asm[(mh * 64 + mt * 16 + kq * 4 + rr) * 128 + nh * 64 + nt * 16 + m] = f2bf(acc[mt][nt][rr]);
  __syncthreads();
  unsigned short* dst = pts_raw + r0 * 128;
  for (int v = t; v < 2048; v += 256)
    *(uint4*)(dst + v * 8) = *(const uint4*)(Asm + v * 8);
}

// =====================================================================
// column sum / sumsq (BN batch statistics)
// =====================================================================
__global__ __launch_bounds__(256) void k_stats(const unsigned short* __restrict__ img_raw,
                                               const unsigned short* __restrict__ pts_raw,
                                               float* __restrict__ stats) {
  const int bid = blockIdx.x;
  const uint32_t* src = (const uint32_t*)((bid < 256) ? img_raw : pts_raw);
  const int blk = bid & 255;
  const int t = threadIdx.x, cp = t & 63, rg = t >> 6;
  float s0 = 0.f, q0 = 0.f, s1 = 0.f, q1 = 0.f;
  for (int i = 0; i < 128; ++i) {
    int row = blk * 512 + rg * 128 + i;
    uint32_t d = src[(size_t)row * 64 + cp];
    float v0 = bflo(d), v1 = bfhi(d);
    s0 += v0; q0 += v0 * v0; s1 += v1; q1 += v1 * v1;
  }
  const int base = (bid < 256) ? 0 : 256;
  atomicAdd(&stats[base + 2 * cp], s0);
  atomicAdd(&stats[base + 2 * cp + 1], s1);
  atomicAdd(&stats[base + 128 + 2 * cp], q0);
  atomicAdd(&stats[base + 128 + 2 * cp + 1], q1);
}

// =====================================================================
// finalize: out = relu(a_img*img + a_pts*pts + c), fp32
// =====================================================================
__global__ __launch_bounds__(256) void k_final(const unsigned short* __restrict__ img_raw,
                                               const unsigned short* __restrict__ pts_raw,
                                               const float* __restrict__ stats,
                                               const float* __restrict__ img_gamma,
                                               const float* __restrict__ img_beta,
                                               const float* __restrict__ pts_gamma,
                                               const float* __restrict__ pts_beta,
                                               float* __restrict__ out) {
  __shared__ float sA[128], sB[128], sC[128];
  const int t = threadIdx.x;
  if (t < 128) {
    const float Nr = 131072.f;
    float mu_i = stats[t] / Nr;
    float var_i = stats[128 + t] / Nr - mu_i * mu_i;
    float a_i = img_gamma[t] * rsqrtf(var_i + 1e-3f);
    float mu_p = stats[256 + t] / Nr;
    float var_p = stats[384 + t] / Nr - mu_p * mu_p;
    float a_p = pts_gamma[t] * rsqrtf(var_p + 1e-3f);
    sA[t] = a_i; sB[t] = a_p;
    sC[t] = img_beta[t] + pts_beta[t] - a_i * mu_i - a_p * mu_p;
  }
  __syncthreads();
  const uint32_t* ir = (const uint32_t*)img_raw;
  const uint32_t* pr = (const uint32_t*)pts_raw;
  size_t g0 = (size_t)blockIdx.x * 2048;
  for (int i = 0; i < 8; ++i) {
    size_t g = g0 + i * 256 + t;
    uint32_t di = ir[g], dp = pr[g];
    int c = (int)(g & 63) * 2;
    float o0 = fmaxf(0.f, sA[c] * bflo(di) + sB[c] * bflo(dp) + sC[c]);
    float o1 = fmaxf(0.f, sA[c + 1] * bfhi(di) + sB[c + 1] * bfhi(dp) + sC[c + 1]);
    float2 o; o.x = o0; o.y = o1;
    *(float2*)(out + g * 2) = o;
  }
}

// =====================================================================
extern "C" void kernel_launch(void* const* d_in, const int* in_sizes, int n_in,
                              void* d_out, int out_size, void* d_ws, size_t ws_size,
                              hipStream_t stream) {
  const float* img_feats = (const float*)d_in[0];
  const float* pts_xyz   = (const float*)d_in[1];
  const float* pts_feats = (const float*)d_in[2];
  const float* Tm        = (const float*)d_in[3];
  const float* Km        = (const float*)d_in[4];
  const float* conv_w    = (const float*)d_in[5];
  const float* conv_b    = (const float*)d_in[6];
  const float* img_w     = (const float*)d_in[7];
  const float* img_gamma = (const float*)d_in[9];
  const float* img_beta  = (const float*)d_in[10];
  const float* pts_w     = (const float*)d_in[11];
  const float* pts_gamma = (const float*)d_in[13];
  const float* pts_beta  = (const float*)d_in[14];
  const int*   cam_ids   = (const int*)d_in[15];

  char* wsb = (char*)d_ws;
  unsigned short* wf      = (unsigned short*)(wsb + OFF_WF);
  float*          bias    = (float*)(wsb + OFF_BIAS);
  unsigned short* pts_wb  = (unsigned short*)(wsb + OFF_PTSWB);
  float*          stats   = (float*)(wsb + OFF_STATS);
  unsigned short* fdat    = (unsigned short*)(wsb + OFF_FDAT);
  unsigned short* imgP    = (unsigned short*)(wsb + OFF_IMGP);
  unsigned short* img_raw = (unsigned short*)(wsb + OFF_IRAW);
  unsigned short* pts_raw = (unsigned short*)(wsb + OFF_PRAW);

  hipMemsetAsync(stats, 0, 2048, stream);
  k_zero<<<dim3(62), dim3(256), 0, stream>>>(imgP);
  k_fold_w<<<dim3(216), dim3(256), 0, stream>>>(img_w, conv_w, wf);
  k_misc<<<dim3(65), dim3(256), 0, stream>>>(img_w, conv_b, pts_w, bias, pts_wb);

  k_nhwc<<<dim3(1920), dim3(256), 0, stream>>>(img_feats, imgP);
  k_conv<<<dim3(588), dim3(256), 0, stream>>>(imgP, wf, bias, fdat);

  k_gather<<<dim3(8192), dim3(256), 0, stream>>>(pts_xyz, cam_ids, Tm, Km, fdat, img_raw);
  k_ptsgemm<<<dim3(1024), dim3(256), 0, stream>>>(pts_feats, pts_wb, pts_raw);
  k_stats<<<dim3(512), dim3(256), 0, stream>>>(img_raw, pts_raw, stats);
  k_final<<<dim3(4096), dim3(256), 0, stream>>>(img_raw, pts_raw, stats,
                                                img_gamma, img_beta, pts_gamma, pts_beta,
                                                (float*)d_out);
}

// Round 3
// 742.324 us; speedup vs baseline: 1.4303x; 1.0156x over previous
//
#include <hip/hip_runtime.h>
#include <cstdint>

// ---------------- problem constants ----------------
#define LVLPOS 75240          // 10*66*114 flat padded positions per level
#define GUARD  256            // zero guard positions before/after imgP data
#define NPART  16             // stats partial copies (atomic contention spread)

using f32x4  = __attribute__((ext_vector_type(4))) float;
using bf16x8 = __attribute__((ext_vector_type(8))) __bf16;

static __device__ __forceinline__ unsigned short f2bf(float f) {
  unsigned int u = __float_as_uint(f);
  u += 0x7fffu + ((u >> 16) & 1u);     // round-to-nearest-even
  return (unsigned short)(u >> 16);
}
static __device__ __forceinline__ float bflo(uint32_t d) { return __uint_as_float(d << 16); }
static __device__ __forceinline__ float bfhi(uint32_t d) { return __uint_as_float(d & 0xffff0000u); }

// ---------------- ws layout (bytes) ----------------
// wf     : [3][ck64:4][tap:9][frag 8192] bf16 (fragment-major folded W)  1,769,472
// bias   : [128] f32                                                           512
// pts_wb : [128][128] bf16, fragment-major                                  32,768
// statsP : [16][512] f32 partials                                           32,768
// fdat   : [75264][128] bf16 (level-summed conv output, padded layout)  19,267,584
// imgP   : [(256+3*75240+256)][256] bf16 flat padded NHWC               115,830,784
// img_raw/pts_raw (each 33,554,432) ALIAS imgP (imgP dead after k_conv)
#define OFF_WF     ((size_t)0)
#define OFF_BIAS   ((size_t)1769472)
#define OFF_PTSWB  ((size_t)1769984)
#define OFF_STATSP ((size_t)1802752)
#define OFF_FDAT   ((size_t)1835520)
#define OFF_IMGP   ((size_t)21103104)
#define OFF_IRAW   OFF_IMGP
#define OFF_PRAW   (OFF_IMGP + (size_t)33554432)

// =====================================================================
// setup: fold weights (432), zero imgP pads (62), bias+pts prepack (65),
// zero statsP (8).  grid 567.
// =====================================================================
__global__ __launch_bounds__(256) void k_setup(const float* __restrict__ img_w,
                                               const float* __restrict__ conv_w,
                                               const float* __restrict__ conv_b,
                                               const float* __restrict__ pts_w,
                                               unsigned short* __restrict__ wf,
                                               float* __restrict__ bias,
                                               unsigned short* __restrict__ pts_wb,
                                               unsigned short* __restrict__ imgP,
                                               float* __restrict__ statsP) {
  __shared__ float smem[12544];                 // iw 64x130 + cw 128x33 = 50176 B
  const int b = blockIdx.x, t = threadIdx.x;
  if (b < 432) {
    // fold: wf[l][ck64][tap][frag]; block = (l, tap, ck32, o-half)
    int z = b >> 1, oh = b & 1;
    int l = z / 72, r = z % 72, tap = r / 8, ckk = r % 8;
    float* iw = smem;                           // [64 o][130]
    float* cw = smem + 8320;                    // [128 mid][33]
    for (int v = t; v < 2048; v += 256) {
      int o = v >> 5, seg = v & 31;
      float4 f = *(const float4*)(img_w + (size_t)(oh * 64 + o) * 384 + l * 128 + seg * 4);
      float* d = iw + o * 130 + seg * 4;
      d[0] = f.x; d[1] = f.y; d[2] = f.z; d[3] = f.w;
    }
    for (int v = t; v < 4096; v += 256) {
      int mid = v >> 5, cj = v & 31;
      cw[mid * 33 + cj] = conv_w[(size_t)((l * 128 + mid) * 256 + ckk * 32 + cj) * 9 + tap];
    }
    __syncthreads();
    const int o64 = t & 63, cs = t >> 6, o = oh * 64 + o64;
    float accs[8];
    #pragma unroll
    for (int ci = 0; ci < 8; ++ci) accs[ci] = 0.f;
    for (int mid = 0; mid < 128; ++mid) {
      float a = iw[o64 * 130 + mid];
      #pragma unroll
      for (int ci = 0; ci < 8; ++ci) accs[ci] = fmaf(a, cw[mid * 33 + cs * 8 + ci], accs[ci]);
    }
    #pragma unroll
    for (int ci = 0; ci < 8; ++ci) {
      int c = ckk * 32 + cs * 8 + ci;           // global input channel
      int ck64 = c >> 6, c64 = c & 63;
      int kh = c64 >> 5, kq3 = (c64 >> 3) & 3, el = c64 & 7;
      size_t idx = (size_t)((l * 4 + ck64) * 9 + tap) * 8192
                 + (size_t)(((o >> 4) * 2 + kh) * 512) + ((o & 15) + 16 * kq3) * 8 + el;
      wf[idx] = f2bf(accs[ci]);
    }
  } else if (b < 494) {
    // zero guards + per-image pad rows
    int z = b - 432;
    size_t base; int n16;
    if (z == 60)      { base = 0; n16 = 8192; }
    else if (z == 61) { base = (size_t)(GUARD + 3 * LVLPOS) * 256; n16 = 8192; }
    else {
      int lvl = z / 20, w = z % 20, n = w >> 1, y = (w & 1) ? 65 : 0;
      base = (size_t)(GUARD + lvl * LVLPOS + (n * 66 + y) * 114) * 256; n16 = 3648;
    }
    uint4 zz = {0u, 0u, 0u, 0u};
    uint4* d = (uint4*)(imgP + base);
    for (int v = t; v < n16; v += 256) d[v] = zz;
  } else if (b < 559) {
    int z = b - 494;
    if (z == 0) {
      if (t < 128) {
        float a = 0.f;
        for (int i = 0; i < 384; ++i) a = fmaf(img_w[t * 384 + i], conv_b[i], a);
        bias[t] = a;
      }
    } else {
      // pts_w -> fragment-major bf16
      int idx = (z - 1) * 256 + t;              // 0..16383
      int o = idx >> 7, k = idx & 127;
      int ks = k >> 5, kq = (k >> 3) & 3, el = k & 7;
      int pos = (ks * 8 + (o >> 4)) * 512 + ((o & 15) + 16 * kq) * 8 + el;
      pts_wb[pos] = f2bf(pts_w[idx]);
    }
  } else {
    int z = b - 559;
    ((float4*)statsP)[z * 256 + t] = (float4){0.f, 0.f, 0.f, 0.f};
  }
}

// =====================================================================
// NCHW fp32 -> flat padded NHWC bf16.  grid 1920 = (lvl, n, y)
// =====================================================================
__global__ __launch_bounds__(256) void k_nhwc(const float* __restrict__ img,
                                              unsigned short* __restrict__ imgP) {
  __shared__ unsigned short tile[256 * 114];   // [c][x]
  const int t = threadIdx.x;
  const int lvl = blockIdx.x / 640, r = blockIdx.x % 640, n = r >> 6, y = r & 63;
  const float4* src4 = (const float4*)(img + (size_t)(lvl * 10 + n) * 1835008 + (size_t)y * 112);
  for (int v = t; v < 7168; v += 256) {
    int c = v / 28, s = v - c * 28;
    float4 f = src4[(size_t)c * 1792 + s];
    uint2 d;
    d.x = (uint32_t)f2bf(f.x) | ((uint32_t)f2bf(f.y) << 16);
    d.y = (uint32_t)f2bf(f.z) | ((uint32_t)f2bf(f.w) << 16);
    *(uint2*)(tile + c * 114 + s * 4) = d;
  }
  __syncthreads();
  uint32_t* dst = (uint32_t*)(imgP + (size_t)(GUARD + lvl * LVLPOS + (n * 66 + y + 1) * 114) * 256);
  for (int v = t; v < 14592; v += 256) {
    int xp = v >> 7, cp = v & 127;
    uint32_t val = 0;
    if (xp >= 1 && xp <= 112) {
      int x = xp - 1;
      val = (uint32_t)tile[(2 * cp) * 114 + x] | ((uint32_t)tile[(2 * cp + 1) * 114 + x] << 16);
    }
    dst[v] = val;
  }
}

// =====================================================================
// Conv: M=64 flat pos/block (grid 1176), N=128, K=6912.
// Per-(lvl,ck,ky) A staging (66 rows x 64c, pitch 72, double-buffered,
// ONE barrier/stage); B fragments loaded register-direct from L2-resident
// fragment-major wf.  LDS 19008 B.
// =====================================================================
#define APITCH 72
static __device__ __forceinline__ void conv_stage(unsigned short* dst,
                                                  const unsigned short* __restrict__ imgP,
                                                  int s, int m0, int t) {
  int lvl = s / 12, r = s - lvl * 12;
  int ck = r / 3, ky = r - ck * 3;
  const unsigned short* base = imgP
      + (size_t)(GUARD + lvl * LVLPOS + m0 - 1 + (ky - 1) * 114) * 256 + ck * 64;
  for (int v = t; v < 528; v += 256) {          // 66 rows x 8 chunks
    int p = v >> 3, seg = v & 7;
    *(uint4*)(dst + p * APITCH + seg * 8) = *(const uint4*)(base + (size_t)p * 256 + seg * 8);
  }
}

static __device__ __forceinline__ void conv_compute(const unsigned short* As_,
                                                    const unsigned short* __restrict__ wf,
                                                    int s, int mh, int nh, int m, int kq,
                                                    f32x4 (&acc)[2][4]) {
  const unsigned short* W0 = wf + (size_t)(3 * s) * 8192 + (nh * 8) * 512 + (m + 16 * kq) * 8;
  #pragma unroll
  for (int kx = 0; kx < 3; ++kx) {
    const unsigned short* Wp = W0 + kx * 8192;
    bf16x8 bv[4][2];
    #pragma unroll
    for (int nt = 0; nt < 4; ++nt) {
      bv[nt][0] = *(const bf16x8*)(Wp + (nt * 2) * 512);
      bv[nt][1] = *(const bf16x8*)(Wp + (nt * 2 + 1) * 512);
    }
    #pragma unroll
    for (int mt = 0; mt < 2; ++mt) {
      const unsigned short* ap = As_ + (mh * 32 + mt * 16 + m + kx) * APITCH + kq * 8;
      bf16x8 a0 = *(const bf16x8*)(ap);
      bf16x8 a1 = *(const bf16x8*)(ap + 32);
      #pragma unroll
      for (int nt = 0; nt < 4; ++nt) {
        acc[mt][nt] = __builtin_amdgcn_mfma_f32_16x16x32_bf16(a0, bv[nt][0], acc[mt][nt], 0, 0, 0);
        acc[mt][nt] = __builtin_amdgcn_mfma_f32_16x16x32_bf16(a1, bv[nt][1], acc[mt][nt], 0, 0, 0);
      }
    }
  }
}

__global__ __launch_bounds__(256, 4) void k_conv(const unsigned short* __restrict__ imgP,
                                                 const unsigned short* __restrict__ wf,
                                                 const float* __restrict__ bias,
                                                 unsigned short* __restrict__ fdat) {
  __shared__ unsigned short As[2][66 * APITCH];
  const int t = threadIdx.x, lane = t & 63, wave = t >> 6;
  const int mh = wave & 1, nh = wave >> 1;
  const int m = lane & 15, kq = lane >> 4;
  const int m0 = blockIdx.x * 64;

  f32x4 acc[2][4];
  #pragma unroll
  for (int i = 0; i < 2; ++i)
    #pragma unroll
    for (int j = 0; j < 4; ++j) acc[i][j] = (f32x4){0.f, 0.f, 0.f, 0.f};

  conv_stage(As[0], imgP, 0, m0, t);
  #pragma unroll 1
  for (int s = 0; s < 36; s += 2) {
    __syncthreads();
    if (s + 1 < 36) conv_stage(As[1], imgP, s + 1, m0, t);
    conv_compute(As[0], wf, s, mh, nh, m, kq, acc);
    __syncthreads();
    if (s + 2 < 36) conv_stage(As[0], imgP, s + 2, m0, t);
    conv_compute(As[1], wf, s + 1, mh, nh, m, kq, acc);
  }
  __syncthreads();

  // epilogue: bias + bf16, LDS repack (overlays As), contiguous store
  unsigned short* Ep = &As[0][0];               // [64][128] = 16384 B <= 19008
  #pragma unroll
  for (int nt = 0; nt < 4; ++nt) {
    int oc = nh * 64 + nt * 16 + m;
    float bv = bias[oc];
    #pragma unroll
    for (int mt = 0; mt < 2; ++mt)
      #pragma unroll
      for (int rr = 0; rr < 4; ++rr)
        Ep[(mh * 32 + mt * 16 + kq * 4 + rr) * 128 + oc] = f2bf(acc[mt][nt][rr] + bv);
  }
  __syncthreads();
  unsigned short* dst = fdat + (size_t)m0 * 128;
  for (int v = t; v < 1024; v += 256)
    *(uint4*)(dst + v * 8) = *(const uint4*)(Ep + v * 8);
}

// =====================================================================
// gather (blocks 0..8191) + pts GEMM (blocks 8192..9215), stats fused.
// LDS 36864 B union.
// =====================================================================
__global__ __launch_bounds__(256) void k_gp(const float* __restrict__ pts_xyz,
                                            const int* __restrict__ cam_ids,
                                            const float* __restrict__ Tm,
                                            const float* __restrict__ Km,
                                            const unsigned short* __restrict__ fdat,
                                            const float* __restrict__ pts_feats,
                                            const unsigned short* __restrict__ pts_wb,
                                            unsigned short* __restrict__ img_raw,
                                            unsigned short* __restrict__ pts_raw,
                                            float* __restrict__ statsP) {
  __shared__ __align__(16) char smem[36864];
  const int t = threadIdx.x, lane = t & 63, wave = t >> 6;

  if (blockIdx.x < 8192) {
    // ---------------- gather + img stats ----------------
    float* sb = (float*)smem;                   // [128] col sums
    float* qb = sb + 128;                       // [128] col sumsq
    if (t < 128) { sb[t] = 0.f; sb[128 + t] = 0.f; }
    __syncthreads();
    const int p0 = blockIdx.x * 16 + wave * 4;
    const uint32_t* fq = (const uint32_t*)fdat;
    float s0 = 0.f, q0 = 0.f, s1 = 0.f, q1 = 0.f;
    for (int j = 0; j < 4; ++j) {
      const int p = p0 + j;
      const int b = p >> 16;
      const int cam = cam_ids[p];
      const float X = pts_xyz[(size_t)p * 3], Y = pts_xyz[(size_t)p * 3 + 1], Z = pts_xyz[(size_t)p * 3 + 2];
      const float* Tc = Tm + cam * 16;
      float pcx = Tc[0] * X + Tc[1] * Y + Tc[2]  * Z + Tc[3];
      float pcy = Tc[4] * X + Tc[5] * Y + Tc[6]  * Z + Tc[7];
      float pcz = Tc[8] * X + Tc[9] * Y + Tc[10] * Z + Tc[11];
      const float* Kc = Km + cam * 9;
      float pimx = Kc[0] * 0.125f * pcx + Kc[1] * pcy          + Kc[2] * 0.125f * pcz;
      float pimy = Kc[3] * pcx          + Kc[4] * 0.125f * pcy + Kc[5] * 0.125f * pcz;
      float pimz = Kc[6] * pcx          + Kc[7] * pcy          + Kc[8] * pcz;
      float u = pimx / pimz, vv = pimy / pimz;
      float px = (u / 112.f) * 111.f;
      float py = (vv / 64.f) * 63.f;
      float x0 = floorf(px), y0 = floorf(py);
      float wx = px - x0, wy = py - y0;
      float cxf[4] = {x0, x0 + 1.f, x0, x0 + 1.f};
      float cyf[4] = {y0, y0, y0 + 1.f, y0 + 1.f};
      float cwt[4] = {(1.f - wx) * (1.f - wy), wx * (1.f - wy), (1.f - wx) * wy, wx * wy};
      const int nimg = b * 5 + cam;
      float wv[4]; int idx[4]; bool any = false;
      #pragma unroll
      for (int c4 = 0; c4 < 4; ++c4) {
        float xf = cxf[c4], yf = cyf[c4];
        bool valid = (xf >= 0.f) && (xf <= 111.f) && (yf >= 0.f) && (yf <= 63.f);
        float w = cwt[c4] * (valid ? 1.f : 0.f);
        int xi = (int)fminf(fmaxf(xf, 0.f), 111.f);
        int yi = (int)fminf(fmaxf(yf, 0.f), 63.f);
        wv[c4] = w;
        idx[c4] = (nimg * 66 + yi + 1) * 114 + xi + 1;
        any = any || (w != 0.f);
      }
      float a0 = 0.f, a1 = 0.f;
      if (any) {
        #pragma unroll
        for (int c4 = 0; c4 < 4; ++c4) {
          uint32_t d = fq[(size_t)idx[c4] * 64 + lane];
          a0 = fmaf(wv[c4], bflo(d), a0);
          a1 = fmaf(wv[c4], bfhi(d), a1);
        }
      }
      s0 += a0; q0 += a0 * a0; s1 += a1; q1 += a1 * a1;
      ((uint32_t*)img_raw)[(size_t)p * 64 + lane] =
          (uint32_t)f2bf(a0) | ((uint32_t)f2bf(a1) << 16);
    }
    atomicAdd(&sb[lane * 2], s0);
    atomicAdd(&sb[lane * 2 + 1], s1);
    atomicAdd(&qb[lane * 2], q0);
    atomicAdd(&qb[lane * 2 + 1], q1);
    __syncthreads();
    if (t < 128) {
      float* sp = statsP + (size_t)(blockIdx.x & (NPART - 1)) * 512;
      atomicAdd(sp + t, sb[t]);
      atomicAdd(sp + 128 + t, qb[t]);
    }
  } else {
    // ---------------- pts GEMM + pts stats ----------------
    const int pb = blockIdx.x - 8192;
    const size_t r0 = (size_t)pb * 128;
    unsigned short* As2 = (unsigned short*)smem;     // [128][136]
    const int mh = wave & 1, nh = wave >> 1;
    const int m = lane & 15, kq = lane >> 4;
    for (int v = t; v < 4096; v += 256) {
      int mm = v >> 5, seg = v & 31;
      float4 f = *(const float4*)(pts_feats + (r0 + mm) * 128 + seg * 4);
      uint2 d;
      d.x = (uint32_t)f2bf(f.x) | ((uint32_t)f2bf(f.y) << 16);
      d.y = (uint32_t)f2bf(f.z) | ((uint32_t)f2bf(f.w) << 16);
      *(uint2*)(As2 + mm * 136 + seg * 4) = d;
    }
    __syncthreads();
    f32x4 acc[4][4];
    #pragma unroll
    for (int i = 0; i < 4; ++i)
      #pragma unroll
      for (int jj = 0; jj < 4; ++jj) acc[i][jj] = (f32x4){0.f, 0.f, 0.f, 0.f};
    #pragma unroll
    for (int ks = 0; ks < 4; ++ks) {
      bf16x8 bv[4];
      #pragma unroll
      for (int nt = 0; nt < 4; ++nt)
        bv[nt] = *(const bf16x8*)(pts_wb + (size_t)((ks * 8 + nh * 4 + nt) * 512) + lane * 8);
      #pragma unroll
      for (int mt = 0; mt < 4; ++mt) {
        bf16x8 af = *(const bf16x8*)(As2 + (mh * 64 + mt * 16 + m) * 136 + ks * 32 + kq * 8);
        #pragma unroll
        for (int nt = 0; nt < 4; ++nt)
          acc[mt][nt] = __builtin_amdgcn_mfma_f32_16x16x32_bf16(af, bv[nt], acc[mt][nt], 0, 0, 0);
      }
    }
    __syncthreads();
    #pragma unroll
    for (int mt = 0; mt < 4; ++mt)
      #pragma unroll
      for (int nt = 0; nt < 4; ++nt)
        #pragma unroll
        for (int rr = 0; rr < 4; ++rr)
          As2[(mh * 64 + mt * 16 + kq * 4 + rr) * 128 + nh * 64 + nt * 16 + m] = f2bf(acc[mt][nt][rr]);
    __syncthreads();
    unsigned short* dst = pts_raw + r0 * 128;
    for (int v = t; v < 2048; v += 256)
      *(uint4*)(dst + v * 8) = *(const uint4*)(As2 + v * 8);
    // column stats from repacked tile
    float* ps = (float*)(smem + 34816);              // [256] sums
    float* pq = ps + 256;                            // -- wait: need within 36864
    // layout: ps at 34816 (1024B = 256 floats), pq at 35840 (256 floats)
    pq = (float*)(smem + 35840);
    {
      int col = t & 127, rh = t >> 7;
      float s = 0.f, q = 0.f;
      for (int i = 0; i < 64; ++i) {
        float v = __uint_as_float((uint32_t)As2[(rh * 64 + i) * 128 + col] << 16);
        s += v; q += v * v;
      }
      ps[rh * 128 + col] = s;
      pq[rh * 128 + col] = q;
    }
    __syncthreads();
    if (t < 128) {
      float* sp = statsP + (size_t)(blockIdx.x & (NPART - 1)) * 512;
      atomicAdd(sp + 256 + t, ps[t] + ps[128 + t]);
      atomicAdd(sp + 384 + t, pq[t] + pq[128 + t]);
    }
  }
}

// =====================================================================
// finalize: reduce statsP, out = relu(a_img*img + a_pts*pts + c), fp32
// =====================================================================
__global__ __launch_bounds__(256) void k_final(const unsigned short* __restrict__ img_raw,
                                               const unsigned short* __restrict__ pts_raw,
                                               const float* __restrict__ statsP,
                                               const float* __restrict__ img_gamma,
                                               const float* __restrict__ img_beta,
                                               const float* __restrict__ pts_gamma,
                                               const float* __restrict__ pts_beta,
                                               float* __restrict__ out) {
  __shared__ float sA[128], sB[128], sC[128];
  const int t = threadIdx.x;
  if (t < 128) {
    float si = 0.f, qi = 0.f, sp = 0.f, qp = 0.f;
    for (int k = 0; k < NPART; ++k) {
      const float* st = statsP + (size_t)k * 512;
      si += st[t]; qi += st[128 + t]; sp += st[256 + t]; qp += st[384 + t];
    }
    const float Nr = 131072.f;
    float mu_i = si / Nr;
    float var_i = qi / Nr - mu_i * mu_i;
    float a_i = img_gamma[t] * rsqrtf(var_i + 1e-3f);
    float mu_p = sp / Nr;
    float var_p = qp / Nr - mu_p * mu_p;
    float a_p = pts_gamma[t] * rsqrtf(var_p + 1e-3f);
    sA[t] = a_i; sB[t] = a_p;
    sC[t] = img_beta[t] + pts_beta[t] - a_i * mu_i - a_p * mu_p;
  }
  __syncthreads();
  const uint32_t* ir = (const uint32_t*)img_raw;
  const uint32_t* pr = (const uint32_t*)pts_raw;
  size_t g0 = (size_t)blockIdx.x * 2048;
  for (int i = 0; i < 8; ++i) {
    size_t g = g0 + i * 256 + t;
    uint32_t di = ir[g], dp = pr[g];
    int c = (int)(g & 63) * 2;
    float o0 = fmaxf(0.f, sA[c] * bflo(di) + sB[c] * bflo(dp) + sC[c]);
    float o1 = fmaxf(0.f, sA[c + 1] * bfhi(di) + sB[c + 1] * bfhi(dp) + sC[c + 1]);
    float2 o; o.x = o0; o.y = o1;
    *(float2*)(out + g * 2) = o;
  }
}

// =====================================================================
extern "C" void kernel_launch(void* const* d_in, const int* in_sizes, int n_in,
                              void* d_out, int out_size, void* d_ws, size_t ws_size,
                              hipStream_t stream) {
  const float* img_feats = (const float*)d_in[0];
  const float* pts_xyz   = (const float*)d_in[1];
  const float* pts_feats = (const float*)d_in[2];
  const float* Tm        = (const float*)d_in[3];
  const float* Km        = (const float*)d_in[4];
  const float* conv_w    = (const float*)d_in[5];
  const float* conv_b    = (const float*)d_in[6];
  const float* img_w     = (const float*)d_in[7];
  // d_in[8] img_b, d_in[12] pts_b cancel under BN mean subtraction
  const float* img_gamma = (const float*)d_in[9];
  const float* img_beta  = (const float*)d_in[10];
  const float* pts_w     = (const float*)d_in[11];
  const float* pts_gamma = (const float*)d_in[13];
  const float* pts_beta  = (const float*)d_in[14];
  const int*   cam_ids   = (const int*)d_in[15];

  char* wsb = (char*)d_ws;
  unsigned short* wf      = (unsigned short*)(wsb + OFF_WF);
  float*          bias    = (float*)(wsb + OFF_BIAS);
  unsigned short* pts_wb  = (unsigned short*)(wsb + OFF_PTSWB);
  float*          statsP  = (float*)(wsb + OFF_STATSP);
  unsigned short* fdat    = (unsigned short*)(wsb + OFF_FDAT);
  unsigned short* imgP    = (unsigned short*)(wsb + OFF_IMGP);
  unsigned short* img_raw = (unsigned short*)(wsb + OFF_IRAW);
  unsigned short* pts_raw = (unsigned short*)(wsb + OFF_PRAW);

  k_setup<<<dim3(567), dim3(256), 0, stream>>>(img_w, conv_w, conv_b, pts_w,
                                               wf, bias, pts_wb, imgP, statsP);
  k_nhwc<<<dim3(1920), dim3(256), 0, stream>>>(img_feats, imgP);
  k_conv<<<dim3(1176), dim3(256), 0, stream>>>(imgP, wf, bias, fdat);
  k_gp<<<dim3(9216), dim3(256), 0, stream>>>(pts_xyz, cam_ids, Tm, Km, fdat,
                                             pts_feats, pts_wb, img_raw, pts_raw, statsP);
  k_final<<<dim3(4096), dim3(256), 0, stream>>>(img_raw, pts_raw, statsP,
                                                img_gamma, img_beta, pts_gamma, pts_beta,
                                                (float*)d_out);
}